// Round 5
// baseline (493.744 us; speedup 1.0000x reference)
//
#include <hip/hip_runtime.h>
#include <hip/hip_bf16.h>

typedef __attribute__((ext_vector_type(8))) short bf16x8;
typedef __attribute__((ext_vector_type(4))) float f32x4;

#define N_TOK 1024
#define HEADS 8
#define DIM_HEAD 64
#define BATCH 8
#define DIMM 512
#define INNER 512
#define QKV_COLS 1536

__device__ inline short f2bf(float f) {
  union { float f; unsigned u; } v;
  v.f = f;
  unsigned r = v.u + 0x7fffu + ((v.u >> 16) & 1u);  // RNE
  return (short)(r >> 16);
}

// ---------------- elementwise fp32 -> bf16 ----------------
__global__ void cvt_bf16_kernel(const float* __restrict__ in, short* __restrict__ out, int n) {
  int i = (blockIdx.x * 256 + threadIdx.x) * 4;
  if (i >= n) return;
  float4 v = *(const float4*)&in[i];
  short4 o;
  o.x = f2bf(v.x); o.y = f2bf(v.y); o.z = f2bf(v.z); o.w = f2bf(v.w);
  *(short4*)&out[i] = o;
}

// ---------------- transpose + convert: W[K][Nc] -> Wt[Nc][K] bf16 ----------------
__global__ void tr_cvt_kernel(const float* __restrict__ W, short* __restrict__ Wt, int K, int Nc) {
  int id = blockIdx.x * 256 + threadIdx.x;
  if (id >= K * Nc) return;
  int n = id % Nc, k = id / Nc;
  Wt[n * K + k] = f2bf(W[id]);
}

// ------- fused EXP bias table: bias2e[idx][h] = exp(rel[idx][h] + 0.01*exp(-factor_h*dis)) -------
__global__ void bias2e_kernel(const float* __restrict__ rel, const float* __restrict__ headsita,
                              float* __restrict__ bias2e) {
  int e = blockIdx.x * 256 + threadIdx.x;
  if (e >= 3969 * HEADS) return;
  int idx = e >> 3, h = e & 7;
  int dr = idx / 63 - 31;
  int dc = idx % 63 - 31;
  float th = headsita[h];
  float factor = 1.f / (2.f * th * th + 1e-10f);
  float dis = (float)(dr * dr + dc * dc) * (1.0f / 1024.0f);
  bias2e[e] = __expf(rel[e] + 0.01f * __expf(-factor * dis));
}

// ---------------- V transpose: qkv V-slice -> Vt[bh][64 d][1024 j] ----------------
__global__ __launch_bounds__(256)
void v_tr_kernel(const short* __restrict__ qkv, short* __restrict__ Vt) {
  __shared__ short T[64][72];
  int t = threadIdx.x;
  int j0 = blockIdx.x * 64;
  int bh = blockIdx.y;
  int b = bh >> 3, h = bh & 7;
  #pragma unroll
  for (int c = 0; c < 2; ++c) {
    int idn = c * 256 + t;
    int j = idn >> 3, dc = (idn & 7) * 8;
    *(int4*)&T[j][dc] =
      *(const int4*)&qkv[(size_t)(b * N_TOK + j0 + j) * QKV_COLS + 2 * INNER + h * DIM_HEAD + dc];
  }
  __syncthreads();
  #pragma unroll
  for (int c = 0; c < 2; ++c) {
    int idn = c * 256 + t;
    int d = idn >> 3, je = (idn & 7) * 8;
    short tmp[8];
    #pragma unroll
    for (int e = 0; e < 8; ++e) tmp[e] = T[je + e][d];
    *(int4*)&Vt[((size_t)bh * 64 + d) * N_TOK + j0 + je] = *(int4*)tmp;
  }
}

// ---------------- bf16 MFMA GEMM with register prefetch ----------------
template<int OUT_BF16, int ADD_BIAS>
__global__ __launch_bounds__(256)
void gemm_kernel(const short* __restrict__ A, const short* __restrict__ Bt,
                 void* __restrict__ C, const float* __restrict__ bias,
                 int M, int Nc, int K)
{
  __shared__ short Ash[128][40];
  __shared__ short Bsh[128][40];
  const int t = threadIdx.x;
  const int lane = t & 63, wave = t >> 6;
  const int wm = wave >> 1, wn = wave & 1;
  const int m0 = blockIdx.y * 128, n0 = blockIdx.x * 128;
  f32x4 acc[4][4] = {};
  int4 sa[2], sb[2];
  #pragma unroll
  for (int c = 0; c < 2; ++c) {
    int id = c * 256 + t, row = id >> 2, kc = (id & 3) * 8;
    sa[c] = *(const int4*)&A[(size_t)(m0 + row) * K + kc];
    sb[c] = *(const int4*)&Bt[(size_t)(n0 + row) * K + kc];
  }
  for (int k0 = 0; k0 < K; k0 += 32) {
    __syncthreads();
    #pragma unroll
    for (int c = 0; c < 2; ++c) {
      int id = c * 256 + t, row = id >> 2, kc = (id & 3) * 8;
      *(int4*)&Ash[row][kc] = sa[c];
      *(int4*)&Bsh[row][kc] = sb[c];
    }
    __syncthreads();
    if (k0 + 32 < K) {
      #pragma unroll
      for (int c = 0; c < 2; ++c) {
        int id = c * 256 + t, row = id >> 2, kc = (id & 3) * 8;
        sa[c] = *(const int4*)&A[(size_t)(m0 + row) * K + k0 + 32 + kc];
        sb[c] = *(const int4*)&Bt[(size_t)(n0 + row) * K + k0 + 32 + kc];
      }
    }
    bf16x8 af[4], bfr[4];
    #pragma unroll
    for (int m = 0; m < 4; ++m)
      af[m] = *(const bf16x8*)&Ash[wm*64 + m*16 + (lane & 15)][(lane >> 4) * 8];
    #pragma unroll
    for (int n = 0; n < 4; ++n)
      bfr[n] = *(const bf16x8*)&Bsh[wn*64 + n*16 + (lane & 15)][(lane >> 4) * 8];
    #pragma unroll
    for (int m = 0; m < 4; ++m)
      #pragma unroll
      for (int n = 0; n < 4; ++n)
        acc[m][n] = __builtin_amdgcn_mfma_f32_16x16x32_bf16(af[m], bfr[n], acc[m][n], 0, 0, 0);
  }
  const int r0 = (lane >> 4) * 4, c0 = lane & 15;
  #pragma unroll
  for (int m = 0; m < 4; ++m)
    #pragma unroll
    for (int n = 0; n < 4; ++n) {
      int col = n0 + wn*64 + n*16 + c0;
      float bv = ADD_BIAS ? bias[col] : 0.f;
      #pragma unroll
      for (int r = 0; r < 4; ++r) {
        int row = m0 + wm*64 + m*16 + r0 + r;
        float v = acc[m][n][r] + bv;
        if (OUT_BF16) ((short*)C)[(size_t)row * Nc + col] = f2bf(v);
        else          ((float*)C)[(size_t)row * Nc + col] = v;
      }
    }
}

// ---------------- row reduction helper (16-lane groups -> cross-wave) ----------------
template<int IS_MAX>
__device__ inline void reduce4(float (&loc)[4], float (&red)[4][16], int wave, int lane) {
  #pragma unroll
  for (int off = 1; off < 16; off <<= 1)
    #pragma unroll
    for (int r = 0; r < 4; ++r) {
      float o = __shfl_xor(loc[r], off);
      loc[r] = IS_MAX ? fmaxf(loc[r], o) : (loc[r] + o);
    }
  __syncthreads();
  if ((lane & 15) == 0)
    #pragma unroll
    for (int r = 0; r < 4; ++r) red[wave][(lane >> 4) * 4 + r] = loc[r];
  __syncthreads();
  #pragma unroll
  for (int r = 0; r < 4; ++r) {
    int rl = (lane >> 4) * 4 + r;
    float a = red[0][rl], b = red[1][rl], c = red[2][rl], d = red[3][rl];
    loc[r] = IS_MAX ? fmaxf(fmaxf(a, b), fmaxf(c, d)) : (a + b + c + d);
  }
}

// ---------------- fused attention v5 ----------------
// v4 but out2 via PLAIN cached stores (L2 write-back coalescing) -- NT caused 2x
// write amplification + vmcnt-drain stalls at barriers.
__global__ __launch_bounds__(256, 3)
void attn_kernel(const short* __restrict__ qkv,
                 const short* __restrict__ Vt,        // [bh][64][1024]
                 const float* __restrict__ bias2e,    // [3969][8] = exp(rel + 0.01*gauss)
                 const int* __restrict__ rpe_p,
                 float* __restrict__ out2,            // softmax(dots0) [B,H,N,N]
                 short* __restrict__ Obuf)            // [B*N][512] bf16
{
  __shared__ short Tile[128 * 72];      // K phase: [128][72]; V phase: [64][136]
  __shared__ short Ps[16][1032];        // also reused as f32 stage[16][516] for out2
  __shared__ float red[4][16];

  const int t = threadIdx.x;
  const int lane = t & 63, wv = t >> 6;
  const int rg = lane >> 4, cl = lane & 15;

  const int id = blockIdx.x;                 // XCD-swizzled mapping (bijective)
  const int bh = (id & 7) * 8 + ((id >> 3) & 7);
  const int i0 = (id >> 6) * 16;
  const int b = bh >> 3, h = bh & 7;
  const size_t rowbase = (size_t)b * N_TOK;

  // ---- Q fragments (direct global) ----
  const size_t qoff = (rowbase + i0 + cl) * QKV_COLS + h * DIM_HEAD;
  const bf16x8 qf0 = *(const bf16x8*)&qkv[qoff + rg * 8];
  const bf16x8 qf1 = *(const bf16x8*)&qkv[qoff + 32 + rg * 8];

  const short* kbase = qkv + rowbase * QKV_COLS + INNER + h * DIM_HEAD;

  // ---- QK^T: 8 steps of 128 K-rows; prefetch regs -> LDS single buffer ----
  int4 stg[4];
  #pragma unroll
  for (int i = 0; i < 4; ++i) {
    int chunk = i * 256 + t, row = chunk >> 3, c = chunk & 7;
    stg[i] = *(const int4*)&kbase[(size_t)row * QKV_COLS + c * 8];
  }
  #pragma unroll
  for (int i = 0; i < 4; ++i) {
    int chunk = i * 256 + t, row = chunk >> 3, c = chunk & 7;
    *(int4*)&Tile[row * 72 + c * 8] = stg[i];
  }
  __syncthreads();

  f32x4 sc[16];
  #pragma unroll
  for (int i = 0; i < 16; ++i) sc[i] = (f32x4){0.f, 0.f, 0.f, 0.f};

  const size_t vtb = (size_t)bh * 64;
  for (int s = 0; s < 8; ++s) {
    if (s < 7) {            // prefetch next K tile
      #pragma unroll
      for (int i = 0; i < 4; ++i) {
        int chunk = i * 256 + t, row = chunk >> 3, c = chunk & 7;
        stg[i] = *(const int4*)&kbase[(size_t)((s + 1) * 128 + row) * QKV_COLS + c * 8];
      }
    } else {                // prefetch V tile 0 (consumed after softmax)
      #pragma unroll
      for (int i = 0; i < 4; ++i) {
        int chunk = i * 256 + t, d = chunk >> 4, c = chunk & 15;
        stg[i] = *(const int4*)&Vt[(vtb + d) * N_TOK + c * 8];
      }
    }
    #pragma unroll
    for (int c64 = 0; c64 < 2; ++c64) {
      int j = c64 * 64 + wv * 16 + cl;
      bf16x8 kb0 = *(const bf16x8*)&Tile[j * 72 + rg * 8];
      bf16x8 kb1 = *(const bf16x8*)&Tile[j * 72 + 32 + rg * 8];
      sc[s*2+c64] = __builtin_amdgcn_mfma_f32_16x16x32_bf16(qf0, kb0, sc[s*2+c64], 0, 0, 0);
      sc[s*2+c64] = __builtin_amdgcn_mfma_f32_16x16x32_bf16(qf1, kb1, sc[s*2+c64], 0, 0, 0);
    }
    if (s < 7) {
      __syncthreads();
      #pragma unroll
      for (int i = 0; i < 4; ++i) {
        int chunk = i * 256 + t, row = chunk >> 3, c = chunk & 7;
        *(int4*)&Tile[row * 72 + c * 8] = stg[i];
      }
      __syncthreads();
    }
  }

  // ---- scale ----
  #pragma unroll
  for (int tt = 0; tt < 16; ++tt)
    #pragma unroll
    for (int r = 0; r < 4; ++r) sc[tt][r] *= 0.125f;

  // ---- softmax0: single exp pass, e0 kept in sc ----
  float mx0[4] = {-1e30f, -1e30f, -1e30f, -1e30f};
  #pragma unroll
  for (int tt = 0; tt < 16; ++tt)
    #pragma unroll
    for (int r = 0; r < 4; ++r) mx0[r] = fmaxf(mx0[r], sc[tt][r]);
  reduce4<1>(mx0, red, wv, lane);

  float sm0[4] = {0.f, 0.f, 0.f, 0.f};
  #pragma unroll
  for (int tt = 0; tt < 16; ++tt)
    #pragma unroll
    for (int r = 0; r < 4; ++r) {
      float e = __expf(sc[tt][r] - mx0[r]);
      sc[tt][r] = e;
      sm0[r] += e;
    }
  reduce4<0>(sm0, red, wv, lane);

  // ---- out2 = e0/sum0, staged via LDS -> full-line 1KB plain wave stores ----
  float* stage = (float*)&Ps[0][0];      // [16][516] f32 == 33024 B (Ps dead here)
  float iv0[4];
  #pragma unroll
  for (int r = 0; r < 4; ++r) iv0[r] = 1.f / sm0[r];
  const size_t o2base = ((size_t)(b * HEADS + h) * N_TOK + i0) * N_TOK;
  #pragma unroll
  for (int c = 0; c < 2; ++c) {
    #pragma unroll
    for (int tq = 0; tq < 8; ++tq) {
      int tt = c * 8 + tq;
      #pragma unroll
      for (int r = 0; r < 4; ++r)
        stage[(rg * 4 + r) * 516 + tq * 64 + wv * 16 + cl] = sc[tt][r] * iv0[r];
    }
    __syncthreads();
    #pragma unroll
    for (int i = 0; i < 8; ++i) {
      int idx = wv * 8 + i, row = idx >> 1, half = idx & 1;
      f32x4 vd = *(const f32x4*)&stage[row * 516 + half * 256 + lane * 4];
      *(f32x4*)&out2[o2base + (size_t)row * N_TOK + c * 512 + half * 256 + lane * 4] = vd;
    }
    __syncthreads();
  }

  // ---- P = e0 * exp(bias) / sum1  (exp(bias) in [~0.9,1.1] -> no overflow risk) ----
  float sm1[4];
  if (rpe_p[0]) {
    const float* bt = bias2e + h;
    sm1[0] = sm1[1] = sm1[2] = sm1[3] = 0.f;
    #pragma unroll
    for (int r = 0; r < 4; ++r) {
      int i = i0 + rg * 4 + r;
      int ri = i >> 5, ci = i & 31;
      #pragma unroll
      for (int tt = 0; tt < 16; ++tt) {
        int j = tt * 64 + wv * 16 + cl;
        int dr = ri - (j >> 5), dc = ci - (j & 31);
        int idx = (dr + 31) * 63 + (dc + 31);
        float v = sc[tt][r] * bt[idx * 8];
        sc[tt][r] = v;
        sm1[r] += v;
      }
    }
    reduce4<0>(sm1, red, wv, lane);
  } else {
    #pragma unroll
    for (int r = 0; r < 4; ++r) sm1[r] = sm0[r];
  }

  #pragma unroll
  for (int r = 0; r < 4; ++r) {
    float iv = 1.f / sm1[r];
    #pragma unroll
    for (int tt = 0; tt < 16; ++tt)
      Ps[rg * 4 + r][tt * 64 + wv * 16 + cl] = f2bf(sc[tt][r] * iv);
  }
  __syncthreads();   // Ps ready

  // ---- PV: 8 steps of 128 j; Vt tiles in Tile as [64][136] ----
  #pragma unroll
  for (int i = 0; i < 4; ++i) {
    int chunk = i * 256 + t, d = chunk >> 4, c = chunk & 15;
    *(int4*)&Tile[d * 136 + c * 8] = stg[i];
  }
  __syncthreads();

  f32x4 oacc = (f32x4){0.f, 0.f, 0.f, 0.f};
  for (int s = 0; s < 8; ++s) {
    if (s < 7) {
      #pragma unroll
      for (int i = 0; i < 4; ++i) {
        int chunk = i * 256 + t, d = chunk >> 4, c = chunk & 15;
        stg[i] = *(const int4*)&Vt[(vtb + d) * N_TOK + (s + 1) * 128 + c * 8];
      }
    }
    #pragma unroll
    for (int jt = 0; jt < 4; ++jt) {
      bf16x8 pa = *(const bf16x8*)&Ps[cl][s * 128 + jt * 32 + rg * 8];
      bf16x8 vb = *(const bf16x8*)&Tile[(wv * 16 + cl) * 136 + jt * 32 + rg * 8];
      oacc = __builtin_amdgcn_mfma_f32_16x16x32_bf16(pa, vb, oacc, 0, 0, 0);
    }
    if (s < 7) {
      __syncthreads();
      #pragma unroll
      for (int i = 0; i < 4; ++i) {
        int chunk = i * 256 + t, d = chunk >> 4, c = chunk & 15;
        *(int4*)&Tile[d * 136 + c * 8] = stg[i];
      }
      __syncthreads();
    }
  }

  #pragma unroll
  for (int r = 0; r < 4; ++r)
    Obuf[(rowbase + i0 + rg * 4 + r) * INNER + h * DIM_HEAD + wv * 16 + cl] = f2bf(oacc[r]);
}

extern "C" void kernel_launch(void* const* d_in, const int* in_sizes, int n_in,
                              void* d_out, int out_size, void* d_ws, size_t ws_size,
                              hipStream_t stream) {
  const float* x    = (const float*)d_in[0];
  const float* Wqkv = (const float*)d_in[1];
  const float* Wout = (const float*)d_in[2];
  const float* bout = (const float*)d_in[3];
  const float* rel  = (const float*)d_in[4];
  const float* sita = (const float*)d_in[5];
  const int*   rpe  = (const int*)d_in[6];

  char* ws = (char*)d_ws;
  short* xb     = (short*)(ws);                 //  8 MB  x bf16 (dead after gemm1)
  short* WqT    = (short*)(ws + 8388608);       //  1.5MB W_qkv^T (dead after gemm1)
  short* WoT    = (short*)(ws + 9961472);       //  0.5MB W_out^T
  short* qkv    = (short*)(ws + 10485760);      // 24 MB  qkv bf16 [8192][1536]
  short* Obuf   = (short*)(ws + 35651584);      //  8 MB  attn-out bf16 [8192][512]
  short* Vt     = (short*)(ws);                 //  8 MB  V^T [64][64][1024] (reuses xb)
  float* bias2e = (float*)(ws + 8388608);       // 127 KB exp'd fused bias (reuses WqT)

  float* out1 = (float*)d_out;
  float* out2 = out1 + (size_t)BATCH * N_TOK * DIMM;

  hipLaunchKernelGGL(cvt_bf16_kernel, dim3(4096), dim3(256), 0, stream,
                     x, xb, BATCH * N_TOK * DIMM);
  hipLaunchKernelGGL(tr_cvt_kernel, dim3((512 * 1536 + 255) / 256), dim3(256), 0, stream,
                     Wqkv, WqT, 512, 1536);
  hipLaunchKernelGGL(tr_cvt_kernel, dim3((512 * 512 + 255) / 256), dim3(256), 0, stream,
                     Wout, WoT, 512, 512);
  hipLaunchKernelGGL((gemm_kernel<1, 0>), dim3(12, 64), dim3(256), 0, stream,
                     xb, WqT, (void*)qkv, (const float*)nullptr, 8192, 1536, 512);
  // xb / WqT regions are dead now -> Vt / bias2e may overwrite them
  hipLaunchKernelGGL(bias2e_kernel, dim3((3969 * HEADS + 255) / 256), dim3(256), 0, stream,
                     rel, sita, bias2e);
  hipLaunchKernelGGL(v_tr_kernel, dim3(16, 64), dim3(256), 0, stream, qkv, Vt);
  hipLaunchKernelGGL(attn_kernel, dim3(4096), dim3(256), 0, stream,
                     qkv, Vt, bias2e, rpe, out2, Obuf);
  hipLaunchKernelGGL((gemm_kernel<0, 1>), dim3(4, 64), dim3(256), 0, stream,
                     Obuf, WoT, d_out, bout, 8192, 512, 512);
}

// Round 6
// 362.351 us; speedup vs baseline: 1.3626x; 1.3626x over previous
//
#include <hip/hip_runtime.h>
#include <hip/hip_bf16.h>

typedef __attribute__((ext_vector_type(8))) short bf16x8;
typedef __attribute__((ext_vector_type(4))) float f32x4;

#define N_TOK 1024
#define HEADS 8
#define DIM_HEAD 64
#define BATCH 8
#define DIMM 512
#define INNER 512
#define QKV_COLS 1536

__device__ inline short f2bf(float f) {
  union { float f; unsigned u; } v;
  v.f = f;
  unsigned r = v.u + 0x7fffu + ((v.u >> 16) & 1u);  // RNE
  return (short)(r >> 16);
}

__device__ inline unsigned pack2bf(float a, float b) {
  return ((unsigned)(unsigned short)f2bf(a)) | (((unsigned)(unsigned short)f2bf(b)) << 16);
}

// ---------------- elementwise fp32 -> bf16 ----------------
__global__ void cvt_bf16_kernel(const float* __restrict__ in, short* __restrict__ out, int n) {
  int i = (blockIdx.x * 256 + threadIdx.x) * 4;
  if (i >= n) return;
  float4 v = *(const float4*)&in[i];
  short4 o;
  o.x = f2bf(v.x); o.y = f2bf(v.y); o.z = f2bf(v.z); o.w = f2bf(v.w);
  *(short4*)&out[i] = o;
}

// ---------------- transpose + convert: W[K][Nc] -> Wt[Nc][K] bf16 ----------------
__global__ void tr_cvt_kernel(const float* __restrict__ W, short* __restrict__ Wt, int K, int Nc) {
  int id = blockIdx.x * 256 + threadIdx.x;
  if (id >= K * Nc) return;
  int n = id % Nc, k = id / Nc;
  Wt[n * K + k] = f2bf(W[id]);
}

// ------- fused EXP bias table: bias2e[idx][h] = exp(rel[idx][h] + 0.01*exp(-factor_h*dis)) -------
__global__ void bias2e_kernel(const float* __restrict__ rel, const float* __restrict__ headsita,
                              float* __restrict__ bias2e) {
  int e = blockIdx.x * 256 + threadIdx.x;
  if (e >= 3969 * HEADS) return;
  int idx = e >> 3, h = e & 7;
  int dr = idx / 63 - 31;
  int dc = idx % 63 - 31;
  float th = headsita[h];
  float factor = 1.f / (2.f * th * th + 1e-10f);
  float dis = (float)(dr * dr + dc * dc) * (1.0f / 1024.0f);
  bias2e[e] = __expf(rel[e] + 0.01f * __expf(-factor * dis));
}

// ---------------- V transpose: qkv V-slice -> Vt[bh][64 d][1024 j] ----------------
__global__ __launch_bounds__(256)
void v_tr_kernel(const short* __restrict__ qkv, short* __restrict__ Vt) {
  __shared__ short T[64][72];
  int t = threadIdx.x;
  int j0 = blockIdx.x * 64;
  int bh = blockIdx.y;
  int b = bh >> 3, h = bh & 7;
  #pragma unroll
  for (int c = 0; c < 2; ++c) {
    int idn = c * 256 + t;
    int j = idn >> 3, dc = (idn & 7) * 8;
    *(int4*)&T[j][dc] =
      *(const int4*)&qkv[(size_t)(b * N_TOK + j0 + j) * QKV_COLS + 2 * INNER + h * DIM_HEAD + dc];
  }
  __syncthreads();
  #pragma unroll
  for (int c = 0; c < 2; ++c) {
    int idn = c * 256 + t;
    int d = idn >> 3, je = (idn & 7) * 8;
    short tmp[8];
    #pragma unroll
    for (int e = 0; e < 8; ++e) tmp[e] = T[je + e][d];
    *(int4*)&Vt[((size_t)bh * 64 + d) * N_TOK + j0 + je] = *(int4*)tmp;
  }
}

// ---------------- bf16 MFMA GEMM with register prefetch ----------------
template<int OUT_BF16, int ADD_BIAS>
__global__ __launch_bounds__(256)
void gemm_kernel(const short* __restrict__ A, const short* __restrict__ Bt,
                 void* __restrict__ C, const float* __restrict__ bias,
                 int M, int Nc, int K)
{
  __shared__ short Ash[128][40];
  __shared__ short Bsh[128][40];
  const int t = threadIdx.x;
  const int lane = t & 63, wave = t >> 6;
  const int wm = wave >> 1, wn = wave & 1;
  const int m0 = blockIdx.y * 128, n0 = blockIdx.x * 128;
  f32x4 acc[4][4] = {};
  int4 sa[2], sb[2];
  #pragma unroll
  for (int c = 0; c < 2; ++c) {
    int id = c * 256 + t, row = id >> 2, kc = (id & 3) * 8;
    sa[c] = *(const int4*)&A[(size_t)(m0 + row) * K + kc];
    sb[c] = *(const int4*)&Bt[(size_t)(n0 + row) * K + kc];
  }
  for (int k0 = 0; k0 < K; k0 += 32) {
    __syncthreads();
    #pragma unroll
    for (int c = 0; c < 2; ++c) {
      int id = c * 256 + t, row = id >> 2, kc = (id & 3) * 8;
      *(int4*)&Ash[row][kc] = sa[c];
      *(int4*)&Bsh[row][kc] = sb[c];
    }
    __syncthreads();
    if (k0 + 32 < K) {
      #pragma unroll
      for (int c = 0; c < 2; ++c) {
        int id = c * 256 + t, row = id >> 2, kc = (id & 3) * 8;
        sa[c] = *(const int4*)&A[(size_t)(m0 + row) * K + k0 + 32 + kc];
        sb[c] = *(const int4*)&Bt[(size_t)(n0 + row) * K + k0 + 32 + kc];
      }
    }
    bf16x8 af[4], bfr[4];
    #pragma unroll
    for (int m = 0; m < 4; ++m)
      af[m] = *(const bf16x8*)&Ash[wm*64 + m*16 + (lane & 15)][(lane >> 4) * 8];
    #pragma unroll
    for (int n = 0; n < 4; ++n)
      bfr[n] = *(const bf16x8*)&Bsh[wn*64 + n*16 + (lane & 15)][(lane >> 4) * 8];
    #pragma unroll
    for (int m = 0; m < 4; ++m)
      #pragma unroll
      for (int n = 0; n < 4; ++n)
        acc[m][n] = __builtin_amdgcn_mfma_f32_16x16x32_bf16(af[m], bfr[n], acc[m][n], 0, 0, 0);
  }
  const int r0 = (lane >> 4) * 4, c0 = lane & 15;
  #pragma unroll
  for (int m = 0; m < 4; ++m)
    #pragma unroll
    for (int n = 0; n < 4; ++n) {
      int col = n0 + wn*64 + n*16 + c0;
      float bv = ADD_BIAS ? bias[col] : 0.f;
      #pragma unroll
      for (int r = 0; r < 4; ++r) {
        int row = m0 + wm*64 + m*16 + r0 + r;
        float v = acc[m][n][r] + bv;
        if (OUT_BF16) ((short*)C)[(size_t)row * Nc + col] = f2bf(v);
        else          ((float*)C)[(size_t)row * Nc + col] = v;
      }
    }
}

// ---------------- fused attention v6: swapped QK^T, barrier-light ----------------
// block = (b,h,16 q-rows), 4 waves. mfma(K,Q) => lane owns S^T[j][i=cl]:
// j = tj*64 + wv*16 + rg*4 + r (tile-interleaved wave ownership), i = i0+cl.
// QK^T: direct-global K frags, no barriers. Softmax: scalar per lane + 2 shfl + LDS hop.
// PV: P^T packed to wave-private LDS (no barrier), Vt frags direct from global.
__global__ __launch_bounds__(256, 4)
void attn_kernel(const short* __restrict__ qkv,
                 const short* __restrict__ Vt,        // [bh][64][1024]
                 const float* __restrict__ bias2e,    // [3969][8] = exp(rel + 0.01*gauss)
                 const int* __restrict__ rpe_p,
                 float* __restrict__ out2,            // softmax(dots0) [B,H,N,N]
                 short* __restrict__ Obuf)            // [B*N][512] bf16
{
  __shared__ __align__(16) char arena[33024];  // time-shared: stage / P_lds / buf
  __shared__ float red0[4][16];
  __shared__ float red1[4][16];

  const int t = threadIdx.x;
  const int lane = t & 63, wv = t >> 6;
  const int rg = lane >> 4, cl = lane & 15;

  const int id = blockIdx.x;                 // XCD-swizzled (bijective): same-bh -> same XCD
  const int bh = (id & 7) * 8 + ((id >> 3) & 7);
  const int i0 = (id >> 6) * 16;
  const int b = bh >> 3, h = bh & 7;
  const size_t rowbase = (size_t)b * N_TOK;

  // ---- Q fragments (B-operand): Q[i0+cl][rg*8 / +32] ----
  const size_t qoff = (rowbase + i0 + cl) * QKV_COLS + h * DIM_HEAD;
  const bf16x8 qf0 = *(const bf16x8*)&qkv[qoff + rg * 8];
  const bf16x8 qf1 = *(const bf16x8*)&qkv[qoff + 32 + rg * 8];

  // ---- QK^T (swapped): sc[tj] rows j = tj*64 + wv*16 + rg*4 + r, col i = i0+cl ----
  const short* krow = qkv + (rowbase + wv * 16 + cl) * QKV_COLS + INNER + h * DIM_HEAD + rg * 8;
  const size_t KSTR = (size_t)64 * QKV_COLS;   // j-tile stride (shorts)
  f32x4 sc[16];
  bf16x8 a0 = *(const bf16x8*)&krow[0];
  bf16x8 a1 = *(const bf16x8*)&krow[32];
  #pragma unroll
  for (int tj = 0; tj < 16; ++tj) {
    bf16x8 n0, n1;
    if (tj < 15) {
      n0 = *(const bf16x8*)&krow[(tj + 1) * KSTR];
      n1 = *(const bf16x8*)&krow[(tj + 1) * KSTR + 32];
    }
    f32x4 z = (f32x4){0.f, 0.f, 0.f, 0.f};
    z = __builtin_amdgcn_mfma_f32_16x16x32_bf16(a0, qf0, z, 0, 0, 0);
    z = __builtin_amdgcn_mfma_f32_16x16x32_bf16(a1, qf1, z, 0, 0, 0);
    sc[tj] = z;
    a0 = n0; a1 = n1;
  }

  // ---- scale + softmax0 (per-lane scalar: row i = i0+cl fixed) ----
  float m = -1e30f;
  #pragma unroll
  for (int tj = 0; tj < 16; ++tj)
    #pragma unroll
    for (int r = 0; r < 4; ++r) {
      sc[tj][r] *= 0.125f;
      m = fmaxf(m, sc[tj][r]);
    }
  m = fmaxf(m, __shfl_xor(m, 16));
  m = fmaxf(m, __shfl_xor(m, 32));
  if (lane < 16) red0[wv][lane] = m;
  __syncthreads();
  m = fmaxf(fmaxf(red0[0][cl], red0[1][cl]), fmaxf(red0[2][cl], red0[3][cl]));

  float s = 0.f;
  #pragma unroll
  for (int tj = 0; tj < 16; ++tj)
    #pragma unroll
    for (int r = 0; r < 4; ++r) {
      float e = __expf(sc[tj][r] - m);
      sc[tj][r] = e;
      s += e;
    }
  s += __shfl_xor(s, 16);
  s += __shfl_xor(s, 32);
  if (lane < 16) red1[wv][lane] = s;
  __syncthreads();
  const float sm0 = red1[0][cl] + red1[1][cl] + red1[2][cl] + red1[3][cl];
  const float iv0 = 1.f / sm0;

  // ---- out2 = e0*iv0 via LDS transpose chunks (256 j x 16 i), full-line stores ----
  float* stage = (float*)arena;                    // [256][17] f32
  const size_t o2base = ((size_t)(b * HEADS + h) * N_TOK + i0) * N_TOK;
  #pragma unroll
  for (int c = 0; c < 4; ++c) {
    #pragma unroll
    for (int tjl = 0; tjl < 4; ++tjl)
      #pragma unroll
      for (int r = 0; r < 4; ++r)
        stage[(tjl * 64 + wv * 16 + rg * 4 + r) * 17 + cl] = sc[c * 4 + tjl][r] * iv0;
    __syncthreads();
    #pragma unroll
    for (int k = 0; k < 4; ++k) {
      int row = wv * 4 + k;
      #pragma unroll
      for (int e = 0; e < 4; ++e) {
        float v = stage[(e * 64 + lane) * 17 + row];
        out2[o2base + (size_t)row * N_TOK + c * 256 + e * 64 + lane] = v;
      }
    }
    __syncthreads();
  }

  // ---- P = e0 * exp(bias) / sum1 ----
  const int i_row = i0 + cl;
  const int ri = i_row >> 5, ci = i_row & 31;
  const int jbase = wv * 16 + rg * 4;
  float iv1;
  if (rpe_p[0]) {
    const float* bt = bias2e + h;
    float s1 = 0.f;
    #pragma unroll
    for (int tj = 0; tj < 16; ++tj)
      #pragma unroll
      for (int r = 0; r < 4; ++r) {
        int j = tj * 64 + jbase + r;
        int dr = ri - (j >> 5), dc = ci - (j & 31);
        int idx = dr * 63 + dc + 1984;
        float v = sc[tj][r] * bt[idx * 8];
        sc[tj][r] = v;
        s1 += v;
      }
    s1 += __shfl_xor(s1, 16);
    s1 += __shfl_xor(s1, 32);
    if (lane < 16) red0[wv][lane] = s1;
    __syncthreads();
    iv1 = 1.f / (red0[0][cl] + red0[1][cl] + red0[2][cl] + red0[3][cl]);
  } else {
    iv1 = iv0;
  }

  // ---- pack P^T to wave-private LDS: P_lds[i=cl][wv*256 + tj*16 + rg*4 + r] bf16 ----
  // wave-private (own columns) -> no __syncthreads needed before PV reads (lgkmcnt only)
  unsigned short* P_lds = (unsigned short*)arena;  // [16][1032]
  #pragma unroll
  for (int tj = 0; tj < 16; ++tj) {
    unsigned u0 = pack2bf(sc[tj][0] * iv1, sc[tj][1] * iv1);
    unsigned u1 = pack2bf(sc[tj][2] * iv1, sc[tj][3] * iv1);
    uint2 uu; uu.x = u0; uu.y = u1;
    *(uint2*)&P_lds[cl * 1032 + wv * 256 + tj * 16 + rg * 4] = uu;
  }

  // ---- PV (swapped): O^T = mfma(Vt-frag, P^T-frag); partial over wave's 256 j ----
  const size_t vtb = (size_t)bh * 64;
  f32x4 oacc[4];
  #pragma unroll
  for (int dt = 0; dt < 4; ++dt) oacc[dt] = (f32x4){0.f, 0.f, 0.f, 0.f};
  const int vcol = (rg >> 1) * 64 + wv * 16 + (rg & 1) * 8;
  #pragma unroll
  for (int w = 0; w < 8; ++w) {
    bf16x8 pb = *(const bf16x8*)&P_lds[cl * 1032 + wv * 256 + (2 * w + (rg >> 1)) * 16 + (rg & 1) * 8];
    #pragma unroll
    for (int dt = 0; dt < 4; ++dt) {
      bf16x8 va = *(const bf16x8*)&Vt[(vtb + dt * 16 + cl) * N_TOK + w * 128 + vcol];
      oacc[dt] = __builtin_amdgcn_mfma_f32_16x16x32_bf16(va, pb, oacc[dt], 0, 0, 0);
    }
  }

  // ---- cross-wave O reduction: buf[wv][i][d] ----
  __syncthreads();                                  // all P_lds reads done before overwrite
  float* buf = (float*)arena;                       // [4][16][65] (pitch 1040 f32/wave)
  #pragma unroll
  for (int dt = 0; dt < 4; ++dt)
    #pragma unroll
    for (int r = 0; r < 4; ++r)
      buf[wv * 1040 + cl * 65 + dt * 16 + rg * 4 + r] = oacc[dt][r];
  __syncthreads();

  const int i_ = t >> 4, dq = t & 15;
  float o[4];
  #pragma unroll
  for (int k = 0; k < 4; ++k) {
    int d = dq * 4 + k;
    o[k] = buf[0 * 1040 + i_ * 65 + d] + buf[1 * 1040 + i_ * 65 + d]
         + buf[2 * 1040 + i_ * 65 + d] + buf[3 * 1040 + i_ * 65 + d];
  }
  short4 os;
  os.x = f2bf(o[0]); os.y = f2bf(o[1]); os.z = f2bf(o[2]); os.w = f2bf(o[3]);
  *(short4*)&Obuf[(rowbase + i0 + i_) * INNER + h * DIM_HEAD + dq * 4] = os;
}

extern "C" void kernel_launch(void* const* d_in, const int* in_sizes, int n_in,
                              void* d_out, int out_size, void* d_ws, size_t ws_size,
                              hipStream_t stream) {
  const float* x    = (const float*)d_in[0];
  const float* Wqkv = (const float*)d_in[1];
  const float* Wout = (const float*)d_in[2];
  const float* bout = (const float*)d_in[3];
  const float* rel  = (const float*)d_in[4];
  const float* sita = (const float*)d_in[5];
  const int*   rpe  = (const int*)d_in[6];

  char* ws = (char*)d_ws;
  short* xb     = (short*)(ws);                 //  8 MB  x bf16 (dead after gemm1)
  short* WqT    = (short*)(ws + 8388608);       //  1.5MB W_qkv^T (dead after gemm1)
  short* WoT    = (short*)(ws + 9961472);       //  0.5MB W_out^T
  short* qkv    = (short*)(ws + 10485760);      // 24 MB  qkv bf16 [8192][1536]
  short* Obuf   = (short*)(ws + 35651584);      //  8 MB  attn-out bf16 [8192][512]
  short* Vt     = (short*)(ws);                 //  8 MB  V^T [64][64][1024] (reuses xb)
  float* bias2e = (float*)(ws + 8388608);       // 127 KB exp'd fused bias (reuses WqT)

  float* out1 = (float*)d_out;
  float* out2 = out1 + (size_t)BATCH * N_TOK * DIMM;

  hipLaunchKernelGGL(cvt_bf16_kernel, dim3(4096), dim3(256), 0, stream,
                     x, xb, BATCH * N_TOK * DIMM);
  hipLaunchKernelGGL(tr_cvt_kernel, dim3((512 * 1536 + 255) / 256), dim3(256), 0, stream,
                     Wqkv, WqT, 512, 1536);
  hipLaunchKernelGGL(tr_cvt_kernel, dim3((512 * 512 + 255) / 256), dim3(256), 0, stream,
                     Wout, WoT, 512, 512);
  hipLaunchKernelGGL((gemm_kernel<1, 0>), dim3(12, 64), dim3(256), 0, stream,
                     xb, WqT, (void*)qkv, (const float*)nullptr, 8192, 1536, 512);
  // xb / WqT regions are dead now -> Vt / bias2e may overwrite them
  hipLaunchKernelGGL(bias2e_kernel, dim3((3969 * HEADS + 255) / 256), dim3(256), 0, stream,
                     rel, sita, bias2e);
  hipLaunchKernelGGL(v_tr_kernel, dim3(16, 64), dim3(256), 0, stream, qkv, Vt);
  hipLaunchKernelGGL(attn_kernel, dim3(4096), dim3(256), 0, stream,
                     qkv, Vt, bias2e, rpe, out2, Obuf);
  hipLaunchKernelGGL((gemm_kernel<0, 1>), dim3(4, 64), dim3(256), 0, stream,
                     Obuf, WoT, d_out, bout, 8192, 512, 512);
}